// Round 2
// baseline (168.281 us; speedup 1.0000x reference)
//
#include <hip/hip_runtime.h>
#include <math.h>

#define H 512
#define W 512
#define BAND 4
#define NQ 11   // 0:s0(mask) 1-4:s1i..s4i 5-8:s1o..s4o 9:tex 10:shape

__device__ __forceinline__ float shfl_up1(float v, int lane) {
    float r = __shfl_up(v, 1);
    return (lane == 0) ? 0.0f : r;
}
__device__ __forceinline__ float shfl_dn1(float v, int lane) {
    float r = __shfl_down(v, 1);
    return (lane == 63) ? 0.0f : r;
}

__device__ __forceinline__ void load_row(const float* __restrict__ base, size_t img_off,
                                         int y, int x0, float* dst) {
    if (y < 0 || y >= H) {
        #pragma unroll
        for (int j = 0; j < 8; j++) dst[j] = 0.0f;
    } else {
        const float4* p = reinterpret_cast<const float4*>(base + img_off + (size_t)y * W + x0);
        float4 a = p[0];
        float4 b = p[1];
        dst[0] = a.x; dst[1] = a.y; dst[2] = a.z; dst[3] = a.w;
        dst[4] = b.x; dst[5] = b.y; dst[6] = b.z; dst[7] = b.w;
    }
}

__global__ __launch_bounds__(256, 4) void radiomics_main(
    const float* __restrict__ inp, const float* __restrict__ outp,
    const float* __restrict__ mask, double* __restrict__ partials)
{
    const int tid = threadIdx.x;
    const int lane = tid & 63;
    const int wib = tid >> 6;                    // wave in block (0..3)
    const int gwave = blockIdx.x * 4 + wib;
    const int bands_per_img = H / BAND;          // 128
    const int b = gwave >> 7;                    // gwave / 128
    const int band = gwave & 127;
    const int y0 = band * BAND;
    const size_t off = (size_t)b * H * W;
    const int x0 = lane * 8;

    // rolling 3-row window per image + current mask row (56 regs of state)
    float Pi[8], Ci[8], Ni[8];
    float Po[8], Co[8], No[8];
    float Mk[8];

    load_row(inp,  off, y0 - 1, x0, Pi);
    load_row(inp,  off, y0,     x0, Ci);
    load_row(inp,  off, y0 + 1, x0, Ni);
    load_row(outp, off, y0 - 1, x0, Po);
    load_row(outp, off, y0,     x0, Co);
    load_row(outp, off, y0 + 1, x0, No);
    load_row(mask, off, y0,     x0, Mk);

    float acc[NQ];
    #pragma unroll
    for (int q = 0; q < NQ; q++) acc[q] = 0.0f;

    const float inv9 = 1.0f / 9.0f;

    #pragma unroll
    for (int i = 0; i < BAND; i++) {
        if (i) {
            // shift window down one row; load only the new rows (no prefetch regs)
            #pragma unroll
            for (int j = 0; j < 8; j++) { Pi[j] = Ci[j]; Ci[j] = Ni[j]; Po[j] = Co[j]; Co[j] = No[j]; }
            load_row(inp,  off, y0 + i + 1, x0, Ni);
            load_row(outp, off, y0 + i + 1, x0, No);
            load_row(mask, off, y0 + i,     x0, Mk);
        }

        // column sums for both images (temps live only inside this iteration)
        float c1i[8], c2i[8], c1o[8], c2o[8];
        #pragma unroll
        for (int j = 0; j < 8; j++) {
            c1i[j] = Pi[j] + Ci[j] + Ni[j];
            c2i[j] = fmaf(Pi[j], Pi[j], fmaf(Ci[j], Ci[j], Ni[j] * Ni[j]));
            c1o[j] = Po[j] + Co[j] + No[j];
            c2o[j] = fmaf(Po[j], Po[j], fmaf(Co[j], Co[j], No[j] * No[j]));
        }
        // horizontal halos via cross-lane shuffle; lane0/63 edges are the true zero padding
        float c1il = shfl_up1(c1i[7], lane), c1ir = shfl_dn1(c1i[0], lane);
        float c2il = shfl_up1(c2i[7], lane), c2ir = shfl_dn1(c2i[0], lane);
        float Cil  = shfl_up1(Ci[7],  lane), Cir  = shfl_dn1(Ci[0],  lane);
        float c1ol = shfl_up1(c1o[7], lane), c1or = shfl_dn1(c1o[0], lane);
        float c2ol = shfl_up1(c2o[7], lane), c2or = shfl_dn1(c2o[0], lane);
        float Col  = shfl_up1(Co[7],  lane), Cor  = shfl_dn1(Co[0],  lane);

        #pragma unroll
        for (int j = 0; j < 8; j++) {
            // input image: local variance + laplacian
            float l1 = (j == 0) ? c1il : c1i[j-1];
            float r1 = (j == 7) ? c1ir : c1i[j+1];
            float l2 = (j == 0) ? c2il : c2i[j-1];
            float r2 = (j == 7) ? c2ir : c2i[j+1];
            float mn = (l1 + c1i[j] + r1) * inv9;
            float tvi = fmaf(-mn, mn, (l2 + c2i[j] + r2) * inv9);
            float cl = (j == 0) ? Cil : Ci[j-1];
            float cr = (j == 7) ? Cir : Ci[j+1];
            float lpi = (c1i[j] - Ci[j]) + cl + cr - 4.0f * Ci[j];
            // output image
            l1 = (j == 0) ? c1ol : c1o[j-1];
            r1 = (j == 7) ? c1or : c1o[j+1];
            l2 = (j == 0) ? c2ol : c2o[j-1];
            r2 = (j == 7) ? c2or : c2o[j+1];
            mn = (l1 + c1o[j] + r1) * inv9;
            float tvo = fmaf(-mn, mn, (l2 + c2o[j] + r2) * inv9);
            cl = (j == 0) ? Col : Co[j-1];
            cr = (j == 7) ? Cor : Co[j+1];
            float lpo = (c1o[j] - Co[j]) + cl + cr - 4.0f * Co[j];

            float m = Mk[j];
            acc[9]  += fabsf(tvo * m - tvi * m);
            acc[10] += fabsf(lpo * m - lpi * m);
            acc[0]  += m;
            float xi = Ci[j];
            float t = xi * m; acc[1] += t; t *= xi; acc[2] += t; t *= xi; acc[3] += t; t *= xi; acc[4] += t;
            float xo = Co[j];
            t = xo * m; acc[5] += t; t *= xo; acc[6] += t; t *= xo; acc[7] += t; t *= xo; acc[8] += t;
        }
    }

    // wave-level fp32 reduce, then fp64 per-block partial (no global atomics)
    #pragma unroll
    for (int q = 0; q < NQ; q++) {
        float v = acc[q];
        #pragma unroll
        for (int o = 32; o > 0; o >>= 1) v += __shfl_down(v, o);
        acc[q] = v;
    }
    __shared__ double red[4][NQ];
    if (lane == 0) {
        #pragma unroll
        for (int q = 0; q < NQ; q++) red[wib][q] = (double)acc[q];
    }
    __syncthreads();
    if (tid < NQ) {
        double s = red[0][tid] + red[1][tid] + red[2][tid] + red[3][tid];
        partials[(size_t)blockIdx.x * NQ + tid] = s;
    }
}

__global__ __launch_bounds__(256) void radiomics_final(
    const double* __restrict__ partials, int nblk, float* __restrict__ out4, double inv_n)
{
    const int tid = threadIdx.x;
    const int lane = tid & 63;
    const int w = tid >> 6;
    double q[NQ];
    #pragma unroll
    for (int k = 0; k < NQ; k++) q[k] = 0.0;
    for (int i = tid; i < nblk; i += 256) {
        #pragma unroll
        for (int k = 0; k < NQ; k++) q[k] += partials[(size_t)i * NQ + k];
    }
    #pragma unroll
    for (int k = 0; k < NQ; k++) {
        #pragma unroll
        for (int o = 32; o > 0; o >>= 1) q[k] += __shfl_down(q[k], o);
    }
    __shared__ double red[4][NQ];
    if (lane == 0) {
        #pragma unroll
        for (int k = 0; k < NQ; k++) red[w][k] = q[k];
    }
    __syncthreads();
    if (tid == 0) {
        double s[NQ];
        #pragma unroll
        for (int k = 0; k < NQ; k++) s[k] = red[0][k] + red[1][k] + red[2][k] + red[3][k];
        const double EPS = 1e-8;
        double S0 = s[0];
        double ms = S0 + EPS;
        double im = s[1] / ms, om = s[5] / ms;
        double im2 = im * im, im3 = im2 * im, im4 = im2 * im2;
        double om2 = om * om, om3 = om2 * om, om4 = om2 * om2;
        double di2 = s[2] - 2.0*im*s[1] + im2*S0;
        double do2 = s[6] - 2.0*om*s[5] + om2*S0;
        double iv = di2 / ms, ov = do2 / ms;
        double di3 = s[3] - 3.0*im*s[2] + 3.0*im2*s[1] - im3*S0;
        double do3 = s[7] - 3.0*om*s[6] + 3.0*om2*s[5] - om3*S0;
        double isk = di3 / (ms * (iv * sqrt(iv) + EPS));
        double osk = do3 / (ms * (ov * sqrt(ov) + EPS));
        double di4 = s[4] - 4.0*im*s[3] + 6.0*im2*s[2] - 4.0*im3*s[1] + im4*S0;
        double do4 = s[8] - 4.0*om*s[7] + 6.0*om2*s[6] - 4.0*om3*s[5] + om4*S0;
        double iku = di4 / (ms * (iv * iv + EPS));
        double oku = do4 / (ms * (ov * ov + EPS));
        double intensity = (im-om)*(im-om) + (iv-ov)*(iv-ov)
                         + (isk-osk)*(isk-osk) + (iku-oku)*(iku-oku);
        double texture = s[9]  * inv_n;
        double shape   = s[10] * inv_n;
        // TEXTURE_W=1.0, SHAPE_W=0.5, INTENSITY_W=1.0
        double total = intensity + texture + 0.5 * shape;
        out4[0] = (float)intensity;
        out4[1] = (float)texture;
        out4[2] = (float)shape;
        out4[3] = (float)total;
    }
}

extern "C" void kernel_launch(void* const* d_in, const int* in_sizes, int n_in,
                              void* d_out, int out_size, void* d_ws, size_t ws_size,
                              hipStream_t stream) {
    const float* inp  = (const float*)d_in[0];
    const float* outp = (const float*)d_in[1];
    const float* mask = (const float*)d_in[2];
    const int total = in_sizes[0];             // 32*1*512*512
    const int nimg  = total / (H * W);         // 32
    const int nwaves = nimg * (H / BAND);      // 4096
    const int nblk   = nwaves / 4;             // 1024 blocks of 256 threads
    double* partials = (double*)d_ws;          // nblk*NQ doubles, fully overwritten

    radiomics_main<<<nblk, 256, 0, stream>>>(inp, outp, mask, partials);
    const double inv_n = 1.0 / (double)total;
    radiomics_final<<<1, 256, 0, stream>>>(partials, nblk, (float*)d_out, inv_n);
}

// Round 3
// 127.200 us; speedup vs baseline: 1.3230x; 1.3230x over previous
//
#include <hip/hip_runtime.h>
#include <math.h>

#define H 512
#define W 512
#define BAND 4
#define NQ 11   // 0:s0(mask) 1-4:s1i..s4i 5-8:s1o..s4o 9:tex 10:shape

__device__ __forceinline__ float shfl_up1(float v, int lane) {
    float r = __shfl_up(v, 1);
    return (lane == 0) ? 0.0f : r;
}
__device__ __forceinline__ float shfl_dn1(float v, int lane) {
    float r = __shfl_down(v, 1);
    return (lane == 63) ? 0.0f : r;
}

__device__ __forceinline__ void load_row(const float* __restrict__ base, size_t img_off,
                                         int y, int x0, float* dst) {
    if (y < 0 || y >= H) {
        #pragma unroll
        for (int j = 0; j < 8; j++) dst[j] = 0.0f;
    } else {
        const float4* p = reinterpret_cast<const float4*>(base + img_off + (size_t)y * W + x0);
        float4 a = p[0];
        float4 b = p[1];
        dst[0] = a.x; dst[1] = a.y; dst[2] = a.z; dst[3] = a.w;
        dst[4] = b.x; dst[5] = b.y; dst[6] = b.z; dst[7] = b.w;
    }
}

// NOTE: no min-waves arg — round 2 showed __launch_bounds__(256,4) makes the
// backend pick a 64-VGPR tier and spill ~370 B/thread (WRITE_SIZE 97 MB).
__global__ __launch_bounds__(256) void radiomics_main(
    const float* __restrict__ inp, const float* __restrict__ outp,
    const float* __restrict__ mask, double* __restrict__ partials)
{
    const int tid = threadIdx.x;
    const int lane = tid & 63;
    const int wib = tid >> 6;                    // wave in block (0..3)
    const int gwave = blockIdx.x * 4 + wib;
    const int b = gwave >> 7;                    // gwave / (H/BAND = 128)
    const int band = gwave & 127;
    const int y0 = band * BAND;
    const size_t off = (size_t)b * H * W;
    const int x0 = lane * 8;

    // rolling 3-row window per image + current mask row
    float Pi[8], Ci[8], Ni[8];
    float Po[8], Co[8], No[8];
    float Mk[8];

    load_row(inp,  off, y0 - 1, x0, Pi);
    load_row(inp,  off, y0,     x0, Ci);
    load_row(inp,  off, y0 + 1, x0, Ni);
    load_row(outp, off, y0 - 1, x0, Po);
    load_row(outp, off, y0,     x0, Co);
    load_row(outp, off, y0 + 1, x0, No);
    load_row(mask, off, y0,     x0, Mk);

    float acc[NQ];
    #pragma unroll
    for (int q = 0; q < NQ; q++) acc[q] = 0.0f;

    const float inv9 = 1.0f / 9.0f;

    #pragma unroll
    for (int i = 0; i < BAND; i++) {
        if (i) {
            #pragma unroll
            for (int j = 0; j < 8; j++) { Pi[j] = Ci[j]; Ci[j] = Ni[j]; Po[j] = Co[j]; Co[j] = No[j]; }
            load_row(inp,  off, y0 + i + 1, x0, Ni);
            load_row(outp, off, y0 + i + 1, x0, No);
            load_row(mask, off, y0 + i,     x0, Mk);
        }

        float t1[8], t2[8];      // column sums (reused for both images)
        float tvm[8], lpm[8];    // input image's masked tex-var / laplacian

        // ---- phase A: input image → tvm/lpm, then release t1/t2 ----
        #pragma unroll
        for (int j = 0; j < 8; j++) {
            t1[j] = Pi[j] + Ci[j] + Ni[j];
            t2[j] = fmaf(Pi[j], Pi[j], fmaf(Ci[j], Ci[j], Ni[j] * Ni[j]));
        }
        {
            float h1l = shfl_up1(t1[7], lane), h1r = shfl_dn1(t1[0], lane);
            float h2l = shfl_up1(t2[7], lane), h2r = shfl_dn1(t2[0], lane);
            float hcl = shfl_up1(Ci[7], lane), hcr = shfl_dn1(Ci[0], lane);
            #pragma unroll
            for (int j = 0; j < 8; j++) {
                float l1 = (j == 0) ? h1l : t1[j-1];
                float r1 = (j == 7) ? h1r : t1[j+1];
                float l2 = (j == 0) ? h2l : t2[j-1];
                float r2 = (j == 7) ? h2r : t2[j+1];
                float mn = (l1 + t1[j] + r1) * inv9;
                float tv = fmaf(-mn, mn, (l2 + t2[j] + r2) * inv9);
                float cl = (j == 0) ? hcl : Ci[j-1];
                float cr = (j == 7) ? hcr : Ci[j+1];
                float lp = (t1[j] - Ci[j]) + cl + cr - 4.0f * Ci[j];
                tvm[j] = tv * Mk[j];
                lpm[j] = lp * Mk[j];
            }
        }

        // ---- phase B: output image, accumulate differences ----
        #pragma unroll
        for (int j = 0; j < 8; j++) {
            t1[j] = Po[j] + Co[j] + No[j];
            t2[j] = fmaf(Po[j], Po[j], fmaf(Co[j], Co[j], No[j] * No[j]));
        }
        {
            float h1l = shfl_up1(t1[7], lane), h1r = shfl_dn1(t1[0], lane);
            float h2l = shfl_up1(t2[7], lane), h2r = shfl_dn1(t2[0], lane);
            float hcl = shfl_up1(Co[7], lane), hcr = shfl_dn1(Co[0], lane);
            #pragma unroll
            for (int j = 0; j < 8; j++) {
                float l1 = (j == 0) ? h1l : t1[j-1];
                float r1 = (j == 7) ? h1r : t1[j+1];
                float l2 = (j == 0) ? h2l : t2[j-1];
                float r2 = (j == 7) ? h2r : t2[j+1];
                float mn = (l1 + t1[j] + r1) * inv9;
                float tv = fmaf(-mn, mn, (l2 + t2[j] + r2) * inv9);
                float cl = (j == 0) ? hcl : Co[j-1];
                float cr = (j == 7) ? hcr : Co[j+1];
                float lp = (t1[j] - Co[j]) + cl + cr - 4.0f * Co[j];
                acc[9]  += fabsf(tv * Mk[j] - tvm[j]);
                acc[10] += fabsf(lp * Mk[j] - lpm[j]);
            }
        }

        // ---- moments ----
        #pragma unroll
        for (int j = 0; j < 8; j++) {
            float m = Mk[j];
            acc[0] += m;
            float xi = Ci[j];
            float t = xi * m; acc[1] += t; t *= xi; acc[2] += t; t *= xi; acc[3] += t; t *= xi; acc[4] += t;
            float xo = Co[j];
            t = xo * m; acc[5] += t; t *= xo; acc[6] += t; t *= xo; acc[7] += t; t *= xo; acc[8] += t;
        }
    }

    // wave-level fp32 reduce, then fp64 per-block partial (no global atomics)
    #pragma unroll
    for (int q = 0; q < NQ; q++) {
        float v = acc[q];
        #pragma unroll
        for (int o = 32; o > 0; o >>= 1) v += __shfl_down(v, o);
        acc[q] = v;
    }
    __shared__ double red[4][NQ];
    if (lane == 0) {
        #pragma unroll
        for (int q = 0; q < NQ; q++) red[wib][q] = (double)acc[q];
    }
    __syncthreads();
    if (tid < NQ) {
        double s = red[0][tid] + red[1][tid] + red[2][tid] + red[3][tid];
        partials[(size_t)blockIdx.x * NQ + tid] = s;
    }
}

__global__ __launch_bounds__(256) void radiomics_final(
    const double* __restrict__ partials, int nblk, float* __restrict__ out4, double inv_n)
{
    const int tid = threadIdx.x;
    const int lane = tid & 63;
    const int w = tid >> 6;
    double q[NQ];
    #pragma unroll
    for (int k = 0; k < NQ; k++) q[k] = 0.0;
    for (int i = tid; i < nblk; i += 256) {
        #pragma unroll
        for (int k = 0; k < NQ; k++) q[k] += partials[(size_t)i * NQ + k];
    }
    #pragma unroll
    for (int k = 0; k < NQ; k++) {
        #pragma unroll
        for (int o = 32; o > 0; o >>= 1) q[k] += __shfl_down(q[k], o);
    }
    __shared__ double red[4][NQ];
    if (lane == 0) {
        #pragma unroll
        for (int k = 0; k < NQ; k++) red[w][k] = q[k];
    }
    __syncthreads();
    if (tid == 0) {
        double s[NQ];
        #pragma unroll
        for (int k = 0; k < NQ; k++) s[k] = red[0][k] + red[1][k] + red[2][k] + red[3][k];
        const double EPS = 1e-8;
        double S0 = s[0];
        double ms = S0 + EPS;
        double im = s[1] / ms, om = s[5] / ms;
        double im2 = im * im, im3 = im2 * im, im4 = im2 * im2;
        double om2 = om * om, om3 = om2 * om, om4 = om2 * om2;
        double di2 = s[2] - 2.0*im*s[1] + im2*S0;
        double do2 = s[6] - 2.0*om*s[5] + om2*S0;
        double iv = di2 / ms, ov = do2 / ms;
        double di3 = s[3] - 3.0*im*s[2] + 3.0*im2*s[1] - im3*S0;
        double do3 = s[7] - 3.0*om*s[6] + 3.0*om2*s[5] - om3*S0;
        double isk = di3 / (ms * (iv * sqrt(iv) + EPS));
        double osk = do3 / (ms * (ov * sqrt(ov) + EPS));
        double di4 = s[4] - 4.0*im*s[3] + 6.0*im2*s[2] - 4.0*im3*s[1] + im4*S0;
        double do4 = s[8] - 4.0*om*s[7] + 6.0*om2*s[6] - 4.0*om3*s[5] + om4*S0;
        double iku = di4 / (ms * (iv * iv + EPS));
        double oku = do4 / (ms * (ov * ov + EPS));
        double intensity = (im-om)*(im-om) + (iv-ov)*(iv-ov)
                         + (isk-osk)*(isk-osk) + (iku-oku)*(iku-oku);
        double texture = s[9]  * inv_n;
        double shape   = s[10] * inv_n;
        // TEXTURE_W=1.0, SHAPE_W=0.5, INTENSITY_W=1.0
        double total = intensity + texture + 0.5 * shape;
        out4[0] = (float)intensity;
        out4[1] = (float)texture;
        out4[2] = (float)shape;
        out4[3] = (float)total;
    }
}

extern "C" void kernel_launch(void* const* d_in, const int* in_sizes, int n_in,
                              void* d_out, int out_size, void* d_ws, size_t ws_size,
                              hipStream_t stream) {
    const float* inp  = (const float*)d_in[0];
    const float* outp = (const float*)d_in[1];
    const float* mask = (const float*)d_in[2];
    const int total = in_sizes[0];             // 32*1*512*512
    const int nimg  = total / (H * W);         // 32
    const int nwaves = nimg * (H / BAND);      // 4096
    const int nblk   = nwaves / 4;             // 1024 blocks of 256 threads
    double* partials = (double*)d_ws;          // nblk*NQ doubles, fully overwritten

    radiomics_main<<<nblk, 256, 0, stream>>>(inp, outp, mask, partials);
    const double inv_n = 1.0 / (double)total;
    radiomics_final<<<1, 256, 0, stream>>>(partials, nblk, (float*)d_out, inv_n);
}

// Round 4
// 126.485 us; speedup vs baseline: 1.3304x; 1.0056x over previous
//
#include <hip/hip_runtime.h>
#include <math.h>

#define H 512
#define W 512
#define BAND 4
#define NQ 11   // 0:s0(mask) 1-4:s1i..s4i 5-8:s1o..s4o 9:tex 10:shape

__device__ __forceinline__ float2 shfl_up1_f2(float2 v, int lane) {
    float2 r;
    r.x = __shfl_up(v.x, 1);
    r.y = __shfl_up(v.y, 1);
    if (lane == 0) { r.x = 0.0f; r.y = 0.0f; }
    return r;
}
__device__ __forceinline__ float2 shfl_dn1_f2(float2 v, int lane) {
    float2 r;
    r.x = __shfl_down(v.x, 1);
    r.y = __shfl_down(v.y, 1);
    if (lane == 63) { r.x = 0.0f; r.y = 0.0f; }
    return r;
}

__device__ __forceinline__ float2 pk_add(float2 a, float2 b) { return make_float2(a.x + b.x, a.y + b.y); }
__device__ __forceinline__ float2 pk_sub(float2 a, float2 b) { return make_float2(a.x - b.x, a.y - b.y); }
__device__ __forceinline__ float2 pk_mul(float2 a, float2 b) { return make_float2(a.x * b.x, a.y * b.y); }
__device__ __forceinline__ float2 pk_muls(float2 a, float s) { return make_float2(a.x * s, a.y * s); }
__device__ __forceinline__ float2 pk_fma(float2 a, float2 b, float2 c) {
    return make_float2(fmaf(a.x, b.x, c.x), fmaf(a.y, b.y, c.y));
}

// load one row of BOTH images, interleaved: dst[j] = (inp[y][x0+j], outp[y][x0+j])
__device__ __forceinline__ void load_row_pk(const float* __restrict__ inp,
                                            const float* __restrict__ outp,
                                            size_t off, int y, int x0, float2* dst) {
    if (y < 0 || y >= H) {
        #pragma unroll
        for (int j = 0; j < 8; j++) dst[j] = make_float2(0.0f, 0.0f);
    } else {
        const float4* pi = reinterpret_cast<const float4*>(inp  + off + (size_t)y * W + x0);
        const float4* po = reinterpret_cast<const float4*>(outp + off + (size_t)y * W + x0);
        float4 a = pi[0], b = pi[1];
        float4 c = po[0], d = po[1];
        dst[0] = make_float2(a.x, c.x); dst[1] = make_float2(a.y, c.y);
        dst[2] = make_float2(a.z, c.z); dst[3] = make_float2(a.w, c.w);
        dst[4] = make_float2(b.x, d.x); dst[5] = make_float2(b.y, d.y);
        dst[6] = make_float2(b.z, d.z); dst[7] = make_float2(b.w, d.w);
    }
}

__device__ __forceinline__ void load_mask_row(const float* __restrict__ mask, size_t off,
                                              int y, int x0, float* dst) {
    const float4* p = reinterpret_cast<const float4*>(mask + off + (size_t)y * W + x0);
    float4 a = p[0];
    float4 b = p[1];
    dst[0] = a.x; dst[1] = a.y; dst[2] = a.z; dst[3] = a.w;
    dst[4] = b.x; dst[5] = b.y; dst[6] = b.z; dst[7] = b.w;
}

// NOTE: no min-waves arg — round 2 showed __launch_bounds__(256,4) forces a
// 64-VGPR tier and spills ~370 B/thread. Packed single-pass structure targets
// <=128 VGPR naturally -> 4 waves/SIMD, matching the 4096-wave grid.
__global__ __launch_bounds__(256) void radiomics_main(
    const float* __restrict__ inp, const float* __restrict__ outp,
    const float* __restrict__ mask, double* __restrict__ partials)
{
    const int tid = threadIdx.x;
    const int lane = tid & 63;
    const int wib = tid >> 6;                    // wave in block (0..3)
    const int gwave = blockIdx.x * 4 + wib;
    const int b = gwave >> 7;                    // gwave / (H/BAND = 128)
    const int band = gwave & 127;
    const int y0 = band * BAND;
    const size_t off = (size_t)b * H * W;
    const int x0 = lane * 8;

    // rolling 3-row packed window (x=inp, y=outp) + current mask row
    float2 P[8], C[8], N[8];
    float  Mk[8];

    load_row_pk(inp, outp, off, y0 - 1, x0, P);
    load_row_pk(inp, outp, off, y0,     x0, C);
    load_row_pk(inp, outp, off, y0 + 1, x0, N);
    load_mask_row(mask, off, y0, x0, Mk);

    float  acc0 = 0.0f, accT = 0.0f, accS = 0.0f;
    float2 am1 = make_float2(0,0), am2 = make_float2(0,0);
    float2 am3 = make_float2(0,0), am4 = make_float2(0,0);

    const float inv9 = 1.0f / 9.0f;

    #pragma unroll
    for (int i = 0; i < BAND; i++) {
        if (i) {
            #pragma unroll
            for (int j = 0; j < 8; j++) { P[j] = C[j]; C[j] = N[j]; }
            load_row_pk(inp, outp, off, y0 + i + 1, x0, N);
            load_mask_row(mask, off, y0 + i, x0, Mk);
        }

        // vertical column sums (packed: both images at once)
        float2 s1[8], s2[8];
        #pragma unroll
        for (int j = 0; j < 8; j++) {
            s1[j] = pk_add(pk_add(P[j], C[j]), N[j]);
            s2[j] = pk_fma(P[j], P[j], pk_fma(C[j], C[j], pk_mul(N[j], N[j])));
        }
        // horizontal halos via cross-lane shuffle; lane0/63 are true zero padding
        float2 h1l = shfl_up1_f2(s1[7], lane), h1r = shfl_dn1_f2(s1[0], lane);
        float2 h2l = shfl_up1_f2(s2[7], lane), h2r = shfl_dn1_f2(s2[0], lane);
        float2 hcl = shfl_up1_f2(C[7],  lane), hcr = shfl_dn1_f2(C[0],  lane);

        #pragma unroll
        for (int j = 0; j < 8; j++) {
            float2 l1 = (j == 0) ? h1l : s1[j-1];
            float2 r1 = (j == 7) ? h1r : s1[j+1];
            float2 l2 = (j == 0) ? h2l : s2[j-1];
            float2 r2 = (j == 7) ? h2r : s2[j+1];
            float2 mn = pk_muls(pk_add(pk_add(l1, s1[j]), r1), inv9);
            float2 e2 = pk_muls(pk_add(pk_add(l2, s2[j]), r2), inv9);
            float2 tv = pk_fma(make_float2(-mn.x, -mn.y), mn, e2);   // E[x^2]-E[x]^2
            float2 cl = (j == 0) ? hcl : C[j-1];
            float2 cr = (j == 7) ? hcr : C[j+1];
            // up+down+left+right-4c = (s1-C) + cl + cr - 4C
            float2 lp = pk_sub(pk_add(pk_add(pk_sub(s1[j], C[j]), cl), cr),
                               pk_muls(C[j], 4.0f));
            float m = Mk[j];
            accT += fabsf(tv.y * m - tv.x * m);
            accS += fabsf(lp.y * m - lp.x * m);
            acc0 += m;
            // raw masked moments, packed (x=inp, y=outp)
            float2 X = C[j];
            float2 t = pk_muls(X, m);
            am1 = pk_add(am1, t); t = pk_mul(t, X);
            am2 = pk_add(am2, t); t = pk_mul(t, X);
            am3 = pk_add(am3, t); t = pk_mul(t, X);
            am4 = pk_add(am4, t);
        }
    }

    // wave-level fp32 reduce, then fp64 per-block partial (no global atomics)
    float acc[NQ] = { acc0, am1.x, am2.x, am3.x, am4.x,
                            am1.y, am2.y, am3.y, am4.y, accT, accS };
    #pragma unroll
    for (int q = 0; q < NQ; q++) {
        float v = acc[q];
        #pragma unroll
        for (int o = 32; o > 0; o >>= 1) v += __shfl_down(v, o);
        acc[q] = v;
    }
    __shared__ double red[4][NQ];
    if (lane == 0) {
        #pragma unroll
        for (int q = 0; q < NQ; q++) red[wib][q] = (double)acc[q];
    }
    __syncthreads();
    if (tid < NQ) {
        double s = red[0][tid] + red[1][tid] + red[2][tid] + red[3][tid];
        partials[(size_t)blockIdx.x * NQ + tid] = s;
    }
}

__global__ __launch_bounds__(256) void radiomics_final(
    const double* __restrict__ partials, int nblk, float* __restrict__ out4, double inv_n)
{
    const int tid = threadIdx.x;
    const int lane = tid & 63;
    const int w = tid >> 6;
    double q[NQ];
    #pragma unroll
    for (int k = 0; k < NQ; k++) q[k] = 0.0;
    for (int i = tid; i < nblk; i += 256) {
        #pragma unroll
        for (int k = 0; k < NQ; k++) q[k] += partials[(size_t)i * NQ + k];
    }
    #pragma unroll
    for (int k = 0; k < NQ; k++) {
        #pragma unroll
        for (int o = 32; o > 0; o >>= 1) q[k] += __shfl_down(q[k], o);
    }
    __shared__ double red[4][NQ];
    if (lane == 0) {
        #pragma unroll
        for (int k = 0; k < NQ; k++) red[w][k] = q[k];
    }
    __syncthreads();
    if (tid == 0) {
        double s[NQ];
        #pragma unroll
        for (int k = 0; k < NQ; k++) s[k] = red[0][k] + red[1][k] + red[2][k] + red[3][k];
        const double EPS = 1e-8;
        double S0 = s[0];
        double ms = S0 + EPS;
        double im = s[1] / ms, om = s[5] / ms;
        double im2 = im * im, im3 = im2 * im, im4 = im2 * im2;
        double om2 = om * om, om3 = om2 * om, om4 = om2 * om2;
        double di2 = s[2] - 2.0*im*s[1] + im2*S0;
        double do2 = s[6] - 2.0*om*s[5] + om2*S0;
        double iv = di2 / ms, ov = do2 / ms;
        double di3 = s[3] - 3.0*im*s[2] + 3.0*im2*s[1] - im3*S0;
        double do3 = s[7] - 3.0*om*s[6] + 3.0*om2*s[5] - om3*S0;
        double isk = di3 / (ms * (iv * sqrt(iv) + EPS));
        double osk = do3 / (ms * (ov * sqrt(ov) + EPS));
        double di4 = s[4] - 4.0*im*s[3] + 6.0*im2*s[2] - 4.0*im3*s[1] + im4*S0;
        double do4 = s[8] - 4.0*om*s[7] + 6.0*om2*s[6] - 4.0*om3*s[5] + om4*S0;
        double iku = di4 / (ms * (iv * iv + EPS));
        double oku = do4 / (ms * (ov * ov + EPS));
        double intensity = (im-om)*(im-om) + (iv-ov)*(iv-ov)
                         + (isk-osk)*(isk-osk) + (iku-oku)*(iku-oku);
        double texture = s[9]  * inv_n;
        double shape   = s[10] * inv_n;
        // TEXTURE_W=1.0, SHAPE_W=0.5, INTENSITY_W=1.0
        double total = intensity + texture + 0.5 * shape;
        out4[0] = (float)intensity;
        out4[1] = (float)texture;
        out4[2] = (float)shape;
        out4[3] = (float)total;
    }
}

extern "C" void kernel_launch(void* const* d_in, const int* in_sizes, int n_in,
                              void* d_out, int out_size, void* d_ws, size_t ws_size,
                              hipStream_t stream) {
    const float* inp  = (const float*)d_in[0];
    const float* outp = (const float*)d_in[1];
    const float* mask = (const float*)d_in[2];
    const int total = in_sizes[0];             // 32*1*512*512
    const int nimg  = total / (H * W);         // 32
    const int nwaves = nimg * (H / BAND);      // 4096
    const int nblk   = nwaves / 4;             // 1024 blocks of 256 threads
    double* partials = (double*)d_ws;          // nblk*NQ doubles, fully overwritten

    radiomics_main<<<nblk, 256, 0, stream>>>(inp, outp, mask, partials);
    const double inv_n = 1.0 / (double)total;
    radiomics_final<<<1, 256, 0, stream>>>(partials, nblk, (float*)d_out, inv_n);
}